// Round 1
// baseline (636.605 us; speedup 1.0000x reference)
//
#include <hip/hip_runtime.h>
#include <hip/hip_bf16.h>
#include <stdint.h>

// LSTM cell: gates = [X|h0](16384x2048) @ Bt^T(2048x4096), fused epilogue.
// bf16 MFMA 16x16x32, 128x128 tiles in gate-interleaved p-space (p = 4*j + t).

typedef __bf16 bf16x8 __attribute__((ext_vector_type(8)));
typedef float f32x4 __attribute__((ext_vector_type(4)));

#define B_ROWS 16384
#define KDIM 2048
#define DH 1024
#define HC_ELEMS 16777216ull  // 16384*1024

__device__ __forceinline__ unsigned short f2bf(float f) {
  unsigned u = __float_as_uint(f);
  u = (u + 0x7fffu + ((u >> 16) & 1u)) >> 16;  // RNE
  return (unsigned short)u;
}

__device__ __forceinline__ float fsig(float x) { return 1.0f / (1.0f + __expf(-x)); }
__device__ __forceinline__ float ftanh_(float x) { return 2.0f / (1.0f + __expf(-2.0f * x)) - 1.0f; }

// A[m][k] = k<1024 ? X[m][k] : h0[m][k-1024], cast to bf16. 8 elems/thread.
__global__ void cast_concat_A(const float* __restrict__ X, const float* __restrict__ h0,
                              unsigned short* __restrict__ A) {
  size_t t = (size_t)blockIdx.x * 256 + threadIdx.x;
  size_t idx = t * 8;
  int m = (int)(idx >> 11);
  int k = (int)(idx & 2047);
  const float* src = (k < 1024) ? (X + (size_t)m * 1024 + k)
                                : (h0 + (size_t)m * 1024 + (k - 1024));
  float4 a = ((const float4*)src)[0];
  float4 b = ((const float4*)src)[1];
  union { unsigned short u[8]; uint4 v; } pk;
  pk.u[0] = f2bf(a.x); pk.u[1] = f2bf(a.y); pk.u[2] = f2bf(a.z); pk.u[3] = f2bf(a.w);
  pk.u[4] = f2bf(b.x); pk.u[5] = f2bf(b.y); pk.u[6] = f2bf(b.z); pk.u[7] = f2bf(b.w);
  *(uint4*)(A + idx) = pk.v;
}

// Bt[n][1024+k'] = W[n][k'] (contiguous copy+cast). 8 elems/thread.
__global__ void cast_W(const float* __restrict__ W, unsigned short* __restrict__ Bt) {
  size_t t = (size_t)blockIdx.x * 256 + threadIdx.x;
  size_t idx = t * 8;  // over 4096*1024
  int n = (int)(idx >> 10);
  int k = (int)(idx & 1023);
  const float* src = W + (size_t)n * 1024 + k;
  float4 a = ((const float4*)src)[0];
  float4 b = ((const float4*)src)[1];
  union { unsigned short u[8]; uint4 v; } pk;
  pk.u[0] = f2bf(a.x); pk.u[1] = f2bf(a.y); pk.u[2] = f2bf(a.z); pk.u[3] = f2bf(a.w);
  pk.u[4] = f2bf(b.x); pk.u[5] = f2bf(b.y); pk.u[6] = f2bf(b.z); pk.u[7] = f2bf(b.w);
  *(uint4*)(Bt + (size_t)n * 2048 + 1024 + k) = pk.v;
}

// Bt[n][k] = U[k][n] for k<1024. 32x32 LDS tile transpose, fp32->bf16.
__global__ void transpose_U(const float* __restrict__ U, unsigned short* __restrict__ Bt) {
  __shared__ float tile[32][33];
  int n0 = blockIdx.x * 32;
  int k0 = blockIdx.y * 32;
  int tx = threadIdx.x & 31, ty = threadIdx.x >> 5;  // ty in [0,8)
  #pragma unroll
  for (int i = 0; i < 4; ++i)
    tile[ty + i * 8][tx] = U[(size_t)(k0 + ty + i * 8) * 4096 + n0 + tx];
  __syncthreads();
  #pragma unroll
  for (int i = 0; i < 4; ++i) {
    int n = n0 + ty + i * 8;
    Bt[(size_t)n * 2048 + k0 + tx] = f2bf(tile[tx][ty + i * 8]);
  }
}

// GEMM + fused LSTM epilogue.
// Grid: (32 p-tiles, 128 m-tiles), 256 threads (4 waves, 2x2 of 64x64).
// LDS: sA[128][64] bf16 @0, sB[128][64] bf16 @16K; 16B blocks XOR-swizzled by (row&7).
// Epilogue reuses sA region: per-wave 4KB chunks, swizzled by row>>2.
__global__ __launch_bounds__(256)
void lstm_gemm(const unsigned short* __restrict__ A, const unsigned short* __restrict__ Bt,
               const float* __restrict__ c0, float* __restrict__ out) {
  __shared__ __align__(16) char smem[32768];
  const int tid = threadIdx.x;
  const int wave = tid >> 6, lane = tid & 63;
  const int q = lane >> 4, cc = lane & 15;
  const int wm = wave >> 1, wn = wave & 1;
  const int m0 = blockIdx.y * 128;
  const int p0 = blockIdx.x * 128;

  f32x4 acc[4][4];
  #pragma unroll
  for (int a = 0; a < 4; ++a)
    #pragma unroll
    for (int b = 0; b < 4; ++b)
      acc[a][b] = f32x4{0.f, 0.f, 0.f, 0.f};

  const int r8 = lane >> 3;            // row within 8-row wave chunk
  const int s8 = (lane & 7) ^ r8;      // swizzled global 16B segment

  for (int k0 = 0; k0 < KDIM; k0 += 64) {
    #pragma unroll
    for (int pass = 0; pass < 4; ++pass) {
      int rl = pass * 32 + wave * 8 + r8;
      // A tile row rl
      const unsigned short* ga = A + (size_t)(m0 + rl) * KDIM + k0 + s8 * 8;
      uintptr_t la = (uintptr_t)(smem + (pass * 32 + wave * 8) * 128);
      __builtin_amdgcn_global_load_lds(
          (const __attribute__((address_space(1))) void*)(uintptr_t)ga,
          (__attribute__((address_space(3))) void*)(uint32_t)la, 16, 0, 0);
      // B tile row rl (p-space -> physical n)
      int p = p0 + rl;
      int n = ((p & 3) << 10) | (p >> 2);
      const unsigned short* gb = Bt + (size_t)n * KDIM + k0 + s8 * 8;
      uintptr_t lb = (uintptr_t)(smem + 16384 + (pass * 32 + wave * 8) * 128);
      __builtin_amdgcn_global_load_lds(
          (const __attribute__((address_space(1))) void*)(uintptr_t)gb,
          (__attribute__((address_space(3))) void*)(uint32_t)lb, 16, 0, 0);
    }
    __syncthreads();
    #pragma unroll
    for (int kk = 0; kk < 2; ++kk) {
      bf16x8 af[4], bfr[4];
      #pragma unroll
      for (int mi = 0; mi < 4; ++mi) {
        int row = wm * 64 + mi * 16 + cc;
        int pos = (kk * 4 + q) ^ (cc & 7);
        af[mi] = *(const bf16x8*)(smem + row * 128 + pos * 16);
      }
      #pragma unroll
      for (int ni = 0; ni < 4; ++ni) {
        int prow = wn * 64 + ni * 16 + cc;
        int pos = (kk * 4 + q) ^ (cc & 7);
        bfr[ni] = *(const bf16x8*)(smem + 16384 + prow * 128 + pos * 16);
      }
      #pragma unroll
      for (int mi = 0; mi < 4; ++mi)
        #pragma unroll
        for (int ni = 0; ni < 4; ++ni)
          acc[mi][ni] = __builtin_amdgcn_mfma_f32_16x16x32_bf16(af[mi], bfr[ni], acc[mi][ni], 0, 0, 0);
    }
    __syncthreads();
  }

  // Fused epilogue. Wave-private 4KB LDS chunk (reuses sA region; safe: the
  // K-loop's trailing barrier guarantees all waves finished LDS reads).
  float* eb = (float*)smem + wave * 1024;
  const int j0 = blockIdx.x * 32;
  #pragma unroll
  for (int mi = 0; mi < 4; ++mi) {
    // Scatter acc (C-layout: row=q*4+r, col=ni*16+cc) into (row, p) layout,
    // 16B blocks swizzled by row>>2 (=q) for conflict reduction.
    #pragma unroll
    for (int ni = 0; ni < 4; ++ni)
      #pragma unroll
      for (int r = 0; r < 4; ++r) {
        int row = q * 4 + r;
        int p = ni * 16 + cc;
        int phys = (p >> 2) ^ q;
        eb[row * 64 + phys * 4 + (p & 3)] = acc[mi][ni][r];
      }
    // Gather (i,f,g,o) as float4 per (row, j); lane -> row=q*4+it, j=cc.
    #pragma unroll
    for (int it = 0; it < 4; ++it) {
      int row = q * 4 + it;
      int phys = cc ^ q;  // row>>2 == q
      f32x4 g4 = *(const f32x4*)(eb + row * 64 + phys * 4);
      int grow = m0 + wm * 64 + mi * 16 + row;
      int gj = j0 + wn * 16 + cc;
      float c0v = c0[(size_t)grow * DH + gj];
      float iv = fsig(g4.x);
      float fv = fsig(g4.y);
      float gv = ftanh_(g4.z);
      float ov = fsig(g4.w);
      float cv = fv * c0v + iv * gv;
      float hv = ov * ftanh_(cv);
      out[(size_t)grow * DH + gj] = hv;
      out[HC_ELEMS + (size_t)grow * DH + gj] = cv;
    }
  }
}

extern "C" void kernel_launch(void* const* d_in, const int* in_sizes, int n_in,
                              void* d_out, int out_size, void* d_ws, size_t ws_size,
                              hipStream_t stream) {
  const float* X  = (const float*)d_in[0];
  const float* h0 = (const float*)d_in[1];
  const float* c0 = (const float*)d_in[2];
  const float* U  = (const float*)d_in[3];
  const float* W  = (const float*)d_in[4];
  float* out = (float*)d_out;

  // ws layout: A_bf16 (16384x2048, 64MB) | Bt_bf16 (4096x2048, 16MB) = 80MB
  unsigned short* Abf = (unsigned short*)d_ws;
  unsigned short* Bt  = Abf + 33554432ull;

  cast_concat_A<<<16384, 256, 0, stream>>>(X, h0, Abf);
  cast_W<<<2048, 256, 0, stream>>>(W, Bt);
  transpose_U<<<dim3(128, 32), 256, 0, stream>>>(U, Bt);
  lstm_gemm<<<dim3(32, 128), 256, 0, stream>>>(Abf, Bt, c0, out);
}

// Round 2
// 619.794 us; speedup vs baseline: 1.0271x; 1.0271x over previous
//
#include <hip/hip_runtime.h>
#include <hip/hip_bf16.h>
#include <stdint.h>

// LSTM cell: gates = [X|h0](16384x2048) @ Bt^T(2048x4096), fused epilogue.
// bf16 MFMA 16x16x32, 128x128 tiles in gate-interleaved p-space (p = 4*j + t).

typedef __bf16 bf16x8 __attribute__((ext_vector_type(8)));
typedef float f32x4 __attribute__((ext_vector_type(4)));

#define B_ROWS 16384
#define KDIM 2048
#define DH 1024
#define HC_ELEMS 16777216ull  // 16384*1024

__device__ __forceinline__ unsigned short f2bf(float f) {
  unsigned u = __float_as_uint(f);
  u = (u + 0x7fffu + ((u >> 16) & 1u)) >> 16;  // RNE
  return (unsigned short)u;
}

// Fast activations: v_rcp_f32 + native exp (no -ffast-math, so 1/x would
// otherwise emit the ~10-instr IEEE div sequence -- 5x per output element).
__device__ __forceinline__ float fsig(float x) {
  return __builtin_amdgcn_rcpf(1.0f + __expf(-x));
}
__device__ __forceinline__ float ftanh_(float x) {
  return 2.0f * __builtin_amdgcn_rcpf(1.0f + __expf(-2.0f * x)) - 1.0f;
}

// A[m][k] = k<1024 ? X[m][k] : h0[m][k-1024], cast to bf16. 8 elems/thread.
__global__ void cast_concat_A(const float* __restrict__ X, const float* __restrict__ h0,
                              unsigned short* __restrict__ A) {
  size_t t = (size_t)blockIdx.x * 256 + threadIdx.x;
  size_t idx = t * 8;
  int m = (int)(idx >> 11);
  int k = (int)(idx & 2047);
  const float* src = (k < 1024) ? (X + (size_t)m * 1024 + k)
                                : (h0 + (size_t)m * 1024 + (k - 1024));
  float4 a = ((const float4*)src)[0];
  float4 b = ((const float4*)src)[1];
  union { unsigned short u[8]; uint4 v; } pk;
  pk.u[0] = f2bf(a.x); pk.u[1] = f2bf(a.y); pk.u[2] = f2bf(a.z); pk.u[3] = f2bf(a.w);
  pk.u[4] = f2bf(b.x); pk.u[5] = f2bf(b.y); pk.u[6] = f2bf(b.z); pk.u[7] = f2bf(b.w);
  *(uint4*)(A + idx) = pk.v;
}

// Bt[n][1024+k'] = W[n][k'] (contiguous copy+cast). 8 elems/thread.
__global__ void cast_W(const float* __restrict__ W, unsigned short* __restrict__ Bt) {
  size_t t = (size_t)blockIdx.x * 256 + threadIdx.x;
  size_t idx = t * 8;  // over 4096*1024
  int n = (int)(idx >> 10);
  int k = (int)(idx & 1023);
  const float* src = W + (size_t)n * 1024 + k;
  float4 a = ((const float4*)src)[0];
  float4 b = ((const float4*)src)[1];
  union { unsigned short u[8]; uint4 v; } pk;
  pk.u[0] = f2bf(a.x); pk.u[1] = f2bf(a.y); pk.u[2] = f2bf(a.z); pk.u[3] = f2bf(a.w);
  pk.u[4] = f2bf(b.x); pk.u[5] = f2bf(b.y); pk.u[6] = f2bf(b.z); pk.u[7] = f2bf(b.w);
  *(uint4*)(Bt + (size_t)n * 2048 + 1024 + k) = pk.v;
}

// Bt[n][k] = U[k][n] for k<1024. 32x32 LDS tile transpose, fp32->bf16,
// ushort4 (8B) vectorized stores.
__global__ void transpose_U(const float* __restrict__ U, unsigned short* __restrict__ Bt) {
  __shared__ float tile[32][33];
  int n0 = blockIdx.x * 32;
  int k0 = blockIdx.y * 32;
  int tx = threadIdx.x & 31, ty = threadIdx.x >> 5;  // ty in [0,8)
  #pragma unroll
  for (int i = 0; i < 4; ++i)
    tile[ty + i * 8][tx] = U[(size_t)(k0 + ty + i * 8) * 4096 + n0 + tx];
  __syncthreads();
  int nrel = threadIdx.x >> 3;          // 0..31
  int kc = (threadIdx.x & 7) * 4;       // 0..28
  union { unsigned short u[4]; uint2 v8; } pk;
  #pragma unroll
  for (int i = 0; i < 4; ++i) pk.u[i] = f2bf(tile[kc + i][nrel]);
  *(uint2*)(Bt + (size_t)(n0 + nrel) * 2048 + k0 + kc) = pk.v8;
}

// GEMM + fused LSTM epilogue.
// Grid: (32 p-tiles, 128 m-tiles), 256 threads (4 waves, 2x2 of 64x64).
// LDS: sA[128][64] bf16 @0, sB[128][64] bf16 @16K; 16B blocks XOR-swizzled by (row&7).
__global__ __launch_bounds__(256)
void lstm_gemm(const unsigned short* __restrict__ A, const unsigned short* __restrict__ Bt,
               const float* __restrict__ c0, float* __restrict__ out) {
  __shared__ __align__(16) char smem[32768];
  const int tid = threadIdx.x;
  const int wave = tid >> 6, lane = tid & 63;
  const int q = lane >> 4, cc = lane & 15;
  const int wm = wave >> 1, wn = wave & 1;
  const int m0 = blockIdx.y * 128;
  const int p0 = blockIdx.x * 128;

  f32x4 acc[4][4];
  #pragma unroll
  for (int a = 0; a < 4; ++a)
    #pragma unroll
    for (int b = 0; b < 4; ++b)
      acc[a][b] = f32x4{0.f, 0.f, 0.f, 0.f};

  const int r8 = lane >> 3;            // row within 8-row wave chunk
  const int s8 = (lane & 7) ^ r8;      // swizzled global 16B segment

  // Strength-reduced staging addresses: 32-bit byte offsets, +128B per k-step.
  uint32_t aoff[4], boff[4];
  #pragma unroll
  for (int pass = 0; pass < 4; ++pass) {
    int rl = pass * 32 + wave * 8 + r8;
    aoff[pass] = (((uint32_t)(m0 + rl) << 11) + (uint32_t)(s8 * 8)) * 2u;
    int p = p0 + rl;
    int n = ((p & 3) << 10) | (p >> 2);
    boff[pass] = (((uint32_t)n << 11) + (uint32_t)(s8 * 8)) * 2u;
  }
  const char* Ab = (const char*)A;
  const char* Bb = (const char*)Bt;

  for (int k0 = 0; k0 < KDIM; k0 += 64) {
    #pragma unroll
    for (int pass = 0; pass < 4; ++pass) {
      uintptr_t la = (uintptr_t)(smem + (pass * 32 + wave * 8) * 128);
      __builtin_amdgcn_global_load_lds(
          (const __attribute__((address_space(1))) void*)(uintptr_t)(Ab + aoff[pass]),
          (__attribute__((address_space(3))) void*)(uint32_t)la, 16, 0, 0);
      uintptr_t lb = (uintptr_t)(smem + 16384 + (pass * 32 + wave * 8) * 128);
      __builtin_amdgcn_global_load_lds(
          (const __attribute__((address_space(1))) void*)(uintptr_t)(Bb + boff[pass]),
          (__attribute__((address_space(3))) void*)(uint32_t)lb, 16, 0, 0);
    }
    #pragma unroll
    for (int pass = 0; pass < 4; ++pass) { aoff[pass] += 128u; boff[pass] += 128u; }
    __syncthreads();
    #pragma unroll
    for (int kk = 0; kk < 2; ++kk) {
      bf16x8 af[4], bfr[4];
      #pragma unroll
      for (int mi = 0; mi < 4; ++mi) {
        int row = wm * 64 + mi * 16 + cc;
        int pos = (kk * 4 + q) ^ (cc & 7);
        af[mi] = *(const bf16x8*)(smem + row * 128 + pos * 16);
      }
      #pragma unroll
      for (int ni = 0; ni < 4; ++ni) {
        int prow = wn * 64 + ni * 16 + cc;
        int pos = (kk * 4 + q) ^ (cc & 7);
        bfr[ni] = *(const bf16x8*)(smem + 16384 + prow * 128 + pos * 16);
      }
      #pragma unroll
      for (int mi = 0; mi < 4; ++mi)
        #pragma unroll
        for (int ni = 0; ni < 4; ++ni)
          acc[mi][ni] = __builtin_amdgcn_mfma_f32_16x16x32_bf16(af[mi], bfr[ni], acc[mi][ni], 0, 0, 0);
    }
    __syncthreads();
  }

  // Fused epilogue. Wave-private 4KB LDS chunk (reuses sA region; safe: the
  // K-loop's trailing barrier guarantees all waves finished LDS reads).
  float* eb = (float*)smem + wave * 1024;
  const int j0 = blockIdx.x * 32;
  #pragma unroll
  for (int mi = 0; mi < 4; ++mi) {
    // Scatter acc (C-layout: row=q*4+r, col=ni*16+cc) into (row, p) layout,
    // 16B blocks swizzled by row>>2 (=q) for conflict reduction.
    #pragma unroll
    for (int ni = 0; ni < 4; ++ni)
      #pragma unroll
      for (int r = 0; r < 4; ++r) {
        int row = q * 4 + r;
        int p = ni * 16 + cc;
        int phys = (p >> 2) ^ q;
        eb[row * 64 + phys * 4 + (p & 3)] = acc[mi][ni][r];
      }
    // Gather (i,f,g,o) as float4 per (row, j); lane -> row=q*4+it, j=cc.
    #pragma unroll
    for (int it = 0; it < 4; ++it) {
      int row = q * 4 + it;
      int phys = cc ^ q;  // row>>2 == q
      f32x4 g4 = *(const f32x4*)(eb + row * 64 + phys * 4);
      int grow = m0 + wm * 64 + mi * 16 + row;
      int gj = j0 + wn * 16 + cc;
      float c0v = c0[(size_t)grow * DH + gj];
      float iv = fsig(g4.x);
      float fv = fsig(g4.y);
      float gv = ftanh_(g4.z);
      float ov = fsig(g4.w);
      float cv = fv * c0v + iv * gv;
      float hv = ov * ftanh_(cv);
      out[(size_t)grow * DH + gj] = hv;
      out[HC_ELEMS + (size_t)grow * DH + gj] = cv;
    }
  }
}

extern "C" void kernel_launch(void* const* d_in, const int* in_sizes, int n_in,
                              void* d_out, int out_size, void* d_ws, size_t ws_size,
                              hipStream_t stream) {
  const float* X  = (const float*)d_in[0];
  const float* h0 = (const float*)d_in[1];
  const float* c0 = (const float*)d_in[2];
  const float* U  = (const float*)d_in[3];
  const float* W  = (const float*)d_in[4];
  float* out = (float*)d_out;

  // ws layout: A_bf16 (16384x2048, 64MB) | Bt_bf16 (4096x2048, 16MB) = 80MB
  unsigned short* Abf = (unsigned short*)d_ws;
  unsigned short* Bt  = Abf + 33554432ull;

  cast_concat_A<<<16384, 256, 0, stream>>>(X, h0, Abf);
  cast_W<<<2048, 256, 0, stream>>>(W, Bt);
  transpose_U<<<dim3(128, 32), 256, 0, stream>>>(U, Bt);
  lstm_gemm<<<dim3(32, 128), 256, 0, stream>>>(Abf, Bt, c0, out);
}

// Round 3
// 590.905 us; speedup vs baseline: 1.0773x; 1.0489x over previous
//
#include <hip/hip_runtime.h>
#include <hip/hip_bf16.h>
#include <stdint.h>

// LSTM cell: gates = [X|h0](16384x2048) @ Bt^T(2048x4096), fused epilogue.
// bf16 MFMA 16x16x32, 128x128 tiles in gate-interleaved p-space.
// Gate mapping chosen so acc[mi][ni] (ni=0..3) = gates i,f,g,o of ONE output
// column in the SAME lane -> epilogue is pure register math (no LDS, no shuffles).

typedef __bf16 bf16x8 __attribute__((ext_vector_type(8)));
typedef float f32x4 __attribute__((ext_vector_type(4)));

#define B_ROWS 16384
#define KDIM 2048
#define DH 1024
#define HC_ELEMS 16777216ull  // 16384*1024

__device__ __forceinline__ unsigned short f2bf(float f) {
  unsigned u = __float_as_uint(f);
  u = (u + 0x7fffu + ((u >> 16) & 1u)) >> 16;  // RNE
  return (unsigned short)u;
}

// Fast activations: v_rcp_f32 + native exp (no -ffast-math => 1/x would emit
// the ~10-instr IEEE div sequence otherwise).
__device__ __forceinline__ float fsig(float x) {
  return __builtin_amdgcn_rcpf(1.0f + __expf(-x));
}
__device__ __forceinline__ float ftanh_(float x) {
  return 2.0f * __builtin_amdgcn_rcpf(1.0f + __expf(-2.0f * x)) - 1.0f;
}

// A[m][k] = k<1024 ? X[m][k] : h0[m][k-1024], cast to bf16. 8 elems/thread.
__global__ void cast_concat_A(const float* __restrict__ X, const float* __restrict__ h0,
                              unsigned short* __restrict__ A) {
  size_t t = (size_t)blockIdx.x * 256 + threadIdx.x;
  size_t idx = t * 8;
  int m = (int)(idx >> 11);
  int k = (int)(idx & 2047);
  const float* src = (k < 1024) ? (X + (size_t)m * 1024 + k)
                                : (h0 + (size_t)m * 1024 + (k - 1024));
  float4 a = ((const float4*)src)[0];
  float4 b = ((const float4*)src)[1];
  union { unsigned short u[8]; uint4 v; } pk;
  pk.u[0] = f2bf(a.x); pk.u[1] = f2bf(a.y); pk.u[2] = f2bf(a.z); pk.u[3] = f2bf(a.w);
  pk.u[4] = f2bf(b.x); pk.u[5] = f2bf(b.y); pk.u[6] = f2bf(b.z); pk.u[7] = f2bf(b.w);
  *(uint4*)(A + idx) = pk.v;
}

// Bt[n][1024+k'] = W[n][k'] (contiguous copy+cast). 8 elems/thread.
__global__ void cast_W(const float* __restrict__ W, unsigned short* __restrict__ Bt) {
  size_t t = (size_t)blockIdx.x * 256 + threadIdx.x;
  size_t idx = t * 8;  // over 4096*1024
  int n = (int)(idx >> 10);
  int k = (int)(idx & 1023);
  const float* src = W + (size_t)n * 1024 + k;
  float4 a = ((const float4*)src)[0];
  float4 b = ((const float4*)src)[1];
  union { unsigned short u[8]; uint4 v; } pk;
  pk.u[0] = f2bf(a.x); pk.u[1] = f2bf(a.y); pk.u[2] = f2bf(a.z); pk.u[3] = f2bf(a.w);
  pk.u[4] = f2bf(b.x); pk.u[5] = f2bf(b.y); pk.u[6] = f2bf(b.z); pk.u[7] = f2bf(b.w);
  *(uint4*)(Bt + (size_t)n * 2048 + 1024 + k) = pk.v;
}

// Bt[n][k] = U[k][n] for k<1024. 32x32 LDS tile transpose, fp32->bf16,
// ushort4 (8B) vectorized stores.
__global__ void transpose_U(const float* __restrict__ U, unsigned short* __restrict__ Bt) {
  __shared__ float tile[32][33];
  int n0 = blockIdx.x * 32;
  int k0 = blockIdx.y * 32;
  int tx = threadIdx.x & 31, ty = threadIdx.x >> 5;  // ty in [0,8)
  #pragma unroll
  for (int i = 0; i < 4; ++i)
    tile[ty + i * 8][tx] = U[(size_t)(k0 + ty + i * 8) * 4096 + n0 + tx];
  __syncthreads();
  int nrel = threadIdx.x >> 3;          // 0..31
  int kc = (threadIdx.x & 7) * 4;       // 0..28
  union { unsigned short u[4]; uint2 v8; } pk;
  #pragma unroll
  for (int i = 0; i < 4; ++i) pk.u[i] = f2bf(tile[kc + i][nrel]);
  *(uint2*)(Bt + (size_t)(n0 + nrel) * 2048 + k0 + kc) = pk.v8;
}

// GEMM + fused LSTM epilogue.
// Grid: (32 p-tiles, 128 m-tiles), 256 threads (4 waves, 2x2 of 64x64).
// LDS: sA[128][64] bf16 @0, sB[128][64] bf16 @16K; 16B blocks XOR-swizzled by (row&7).
// B LDS row rl (= p_local) holds physical n = ((rl>>4)&3)*1024 + j0 + (rl>>6)*16 + (rl&15)
// so that acc[mi][ni] = gate ni of column j0 + wn*16 + cc.
__global__ __launch_bounds__(256)
void lstm_gemm(const unsigned short* __restrict__ A, const unsigned short* __restrict__ Bt,
               const float* __restrict__ c0, float* __restrict__ out) {
  __shared__ __align__(16) char smem[32768];
  const int tid = threadIdx.x;
  const int wave = tid >> 6, lane = tid & 63;
  const int q = lane >> 4, cc = lane & 15;
  const int wm = wave >> 1, wn = wave & 1;
  const int m0 = blockIdx.y * 128;
  const int j0 = blockIdx.x * 32;

  f32x4 acc[4][4];
  #pragma unroll
  for (int a = 0; a < 4; ++a)
    #pragma unroll
    for (int b = 0; b < 4; ++b)
      acc[a][b] = f32x4{0.f, 0.f, 0.f, 0.f};

  const int r8 = lane >> 3;            // row within 8-row wave chunk
  const int s8 = (lane & 7) ^ r8;      // swizzled global 16B segment

  // Strength-reduced staging addresses: 32-bit byte offsets, +128B per k-step.
  uint32_t aoff[4], boff[4];
  #pragma unroll
  for (int pass = 0; pass < 4; ++pass) {
    int rl = pass * 32 + wave * 8 + r8;       // LDS tile row [0,128)
    aoff[pass] = (((uint32_t)(m0 + rl) << 11) + (uint32_t)(s8 * 8)) * 2u;
    // gate-register mapping: t = (rl>>4)&3, j = j0 + (rl>>6)*16 + (rl&15)
    int n = (((rl >> 4) & 3) << 10) + j0 + ((rl >> 6) << 4) + (rl & 15);
    boff[pass] = (((uint32_t)n << 11) + (uint32_t)(s8 * 8)) * 2u;
  }
  const char* Ab = (const char*)A;
  const char* Bb = (const char*)Bt;

  for (int k0 = 0; k0 < KDIM; k0 += 64) {
    #pragma unroll
    for (int pass = 0; pass < 4; ++pass) {
      uintptr_t la = (uintptr_t)(smem + (pass * 32 + wave * 8) * 128);
      __builtin_amdgcn_global_load_lds(
          (const __attribute__((address_space(1))) void*)(uintptr_t)(Ab + aoff[pass]),
          (__attribute__((address_space(3))) void*)(uint32_t)la, 16, 0, 0);
      uintptr_t lb = (uintptr_t)(smem + 16384 + (pass * 32 + wave * 8) * 128);
      __builtin_amdgcn_global_load_lds(
          (const __attribute__((address_space(1))) void*)(uintptr_t)(Bb + boff[pass]),
          (__attribute__((address_space(3))) void*)(uint32_t)lb, 16, 0, 0);
    }
    #pragma unroll
    for (int pass = 0; pass < 4; ++pass) { aoff[pass] += 128u; boff[pass] += 128u; }
    __syncthreads();
    #pragma unroll
    for (int kk = 0; kk < 2; ++kk) {
      bf16x8 af[4], bfr[4];
      #pragma unroll
      for (int mi = 0; mi < 4; ++mi) {
        int row = wm * 64 + mi * 16 + cc;
        int pos = (kk * 4 + q) ^ (cc & 7);
        af[mi] = *(const bf16x8*)(smem + row * 128 + pos * 16);
      }
      #pragma unroll
      for (int ni = 0; ni < 4; ++ni) {
        int prow = wn * 64 + ni * 16 + cc;
        int pos = (kk * 4 + q) ^ (cc & 7);
        bfr[ni] = *(const bf16x8*)(smem + 16384 + prow * 128 + pos * 16);
      }
      #pragma unroll
      for (int mi = 0; mi < 4; ++mi)
        #pragma unroll
        for (int ni = 0; ni < 4; ++ni)
          acc[mi][ni] = __builtin_amdgcn_mfma_f32_16x16x32_bf16(af[mi], bfr[ni], acc[mi][ni], 0, 0, 0);
    }
    __syncthreads();
  }

  // Register-local fused epilogue: acc[mi][0..3] = i,f,g,o of (grow, gj).
  // C-layout: col = lane&15 (matches cc), row = q*4 + r.
  const int gj = j0 + wn * 16 + cc;
  #pragma unroll
  for (int mi = 0; mi < 4; ++mi) {
    #pragma unroll
    for (int r = 0; r < 4; ++r) {
      int grow = m0 + wm * 64 + mi * 16 + q * 4 + r;
      float iv = fsig(acc[mi][0][r]);
      float fv = fsig(acc[mi][1][r]);
      float gv = ftanh_(acc[mi][2][r]);
      float ov = fsig(acc[mi][3][r]);
      float c0v = c0[(size_t)grow * DH + gj];
      float cv = fv * c0v + iv * gv;
      float hv = ov * ftanh_(cv);
      out[(size_t)grow * DH + gj] = hv;
      out[HC_ELEMS + (size_t)grow * DH + gj] = cv;
    }
  }
}

extern "C" void kernel_launch(void* const* d_in, const int* in_sizes, int n_in,
                              void* d_out, int out_size, void* d_ws, size_t ws_size,
                              hipStream_t stream) {
  const float* X  = (const float*)d_in[0];
  const float* h0 = (const float*)d_in[1];
  const float* c0 = (const float*)d_in[2];
  const float* U  = (const float*)d_in[3];
  const float* W  = (const float*)d_in[4];
  float* out = (float*)d_out;

  // ws layout: A_bf16 (16384x2048, 64MB) | Bt_bf16 (4096x2048, 16MB) = 80MB
  unsigned short* Abf = (unsigned short*)d_ws;
  unsigned short* Bt  = Abf + 33554432ull;

  cast_concat_A<<<16384, 256, 0, stream>>>(X, h0, Abf);
  cast_W<<<2048, 256, 0, stream>>>(W, Bt);
  transpose_U<<<dim3(128, 32), 256, 0, stream>>>(U, Bt);
  lstm_gemm<<<dim3(32, 128), 256, 0, stream>>>(Abf, Bt, c0, out);
}